// Round 7
// baseline (47.186 us; speedup 1.0000x reference)
//
#include <hip/hip_runtime.h>

#define NF   784
#define ZD   64
#define BXN  256
#define BZN  4096
#define KDIM 3136    // 4*NF
#define LCOL 1568    // 2*NF logit columns

typedef __attribute__((ext_vector_type(8))) short bf16x8;
typedef __attribute__((ext_vector_type(4))) float f32x4;
typedef __attribute__((ext_vector_type(8))) unsigned short ushort8;

__device__ __forceinline__ unsigned short f2bf(float f) {
  unsigned u = __float_as_uint(f);
  u += 0x7fff + ((u >> 16) & 1);   // round-to-nearest-even
  return (unsigned short)(u >> 16);
}

// ---------------- Kernel 1: prep (fused) ----------------
__global__ __launch_bounds__(256) void prep(const float* __restrict__ x,
                                            const float* __restrict__ z,
                                            const float* __restrict__ W,
                                            const int* __restrict__ tree,
                                            unsigned short* __restrict__ Amat,
                                            unsigned short* __restrict__ zb,
                                            unsigned short* __restrict__ Wt) {
  int bid = blockIdx.x, tid = threadIdx.x;
  if (bid < 1024) {                       // ---- build_a
    int b = bid >> 2;
    int j = (bid & 3) * 256 + tid;
    if (j >= NF) return;
    float xb = x[b * NF + j];
    int idx = tree[j];
    int gidx = idx < 0 ? idx + NF : idx;  // JAX negative-index wrap
    float xt = x[b * NF + gidx];
    ushort4 v;
    v.x = f2bf((1.f - xt) * xb);
    v.y = f2bf(xt * xb);
    v.z = f2bf((1.f - xt) * (1.f - xb));
    v.w = f2bf(xt * (1.f - xb));
    *(ushort4*)&Amat[(size_t)b * KDIM + 4 * j] = v;
  } else if (bid < 1280) {                // ---- z -> bf16
    int t = (bid - 1024) * 256 + tid;
    float4 v = *(const float4*)&z[t * 4];
    ushort4 o = { f2bf(v.x), f2bf(v.y), f2bf(v.z), f2bf(v.w) };
    *(ushort4*)&zb[t * 4] = o;
  } else {                                // ---- W -> Wt (transpose)
    int t = (bid - 1280) * 256 + tid;
    int c = t >> 4, k0 = (t & 15) * 4;
    ushort4 o;
    o.x = f2bf(W[(k0 + 0) * LCOL + c]);
    o.y = f2bf(W[(k0 + 1) * LCOL + c]);
    o.z = f2bf(W[(k0 + 2) * LCOL + c]);
    o.w = f2bf(W[(k0 + 3) * LCOL + c]);
    *(ushort4*)&Wt[c * 64 + k0] = o;
  }
}

// ---------------- Kernel 2: FUSED logits+logsigmoid+GEMM, A direct-from-L2 ----------------
// 512 blocks (64 nt x 8 ks) x 512 thr (8 waves). Wave w owns b-rows [32w,32w+32).
// Waves 0-3 also produce the 16-col logit tile (once, no duplication).
// Only B lives in LDS (2 x 64 x LP shorts, dbuf, ONE barrier/step).
// A-frags: MFMA layout == global layout (row=fr, k=8hi..) -> 64B-coalesced L2 loads.
#define LP 40
__global__ __launch_bounds__(512, 4) void gemm_fused(const unsigned short* __restrict__ Amat,
                                                     const unsigned short* __restrict__ zb,
                                                     const unsigned short* __restrict__ Wt,
                                                     const float* __restrict__ bias,
                                                     const int* __restrict__ tree,
                                                     float* __restrict__ part) {
  __shared__ unsigned short Bs[2][64][LP];   // 10240 B
  int bid = blockIdx.x;                      // 512 = 64 n-tiles x 8 k-splits
  int s = bid & 7, nt = bid >> 3;
  int n0 = nt * 64;
  int kt0 = s * 12 + (s < 2 ? s : 2);        // 98 = 13+13+12*6
  int nsteps = (s < 2) ? 13 : 12;
  int tid = threadIdx.x;
  int w = tid >> 6, lane = tid & 63;
  int fr = lane & 15, hi = lane >> 4, kq = hi * 8;

  // z fragments for logit waves (w<4): 16 z-rows each, resident all steps.
  bf16x8 zf0, zf1;
  if (w < 4) {
    const unsigned short* zp = zb + (size_t)(n0 + w * 16 + fr) * 64 + kq;
    zf0 = *(const bf16x8*)zp;
    zf1 = *(const bf16x8*)(zp + 32);
  }

  // A base: this wave's fragment rows (32w+16m+fr), k-slot kq
  const unsigned short* Ag = Amat + (size_t)(w * 32 + fr) * KDIM + kq;

  f32x4 acc[2][4];
#pragma unroll
  for (int m = 0; m < 2; ++m)
#pragma unroll
    for (int n = 0; n < 4; ++n) acc[m][n] = (f32x4){0.f, 0.f, 0.f, 0.f};

  int buf = 0;
  for (int i = 0; i < nsteps; ++i) {
    int kt = kt0 + i;
    int k0 = kt * 32;
    if (w < 4) {
      // --- logits for cols [16kt,16kt+16) x z-rows [n0+16w, n0+16w+16)
      const unsigned short* wp = Wt + (size_t)(kt * 16 + fr) * 64 + kq;
      bf16x8 wf0 = *(const bf16x8*)wp;
      bf16x8 wf1 = *(const bf16x8*)(wp + 32);
      f32x4 lacc = (f32x4){0.f, 0.f, 0.f, 0.f};
      lacc = __builtin_amdgcn_mfma_f32_16x16x32_bf16(wf0, zf0, lacc, 0, 0, 0);
      lacc = __builtin_amdgcn_mfma_f32_16x16x32_bf16(wf1, zf1, lacc, 0, 0, 0);
      // --- log-sigmoid epilogue: lane holds logit cols 16kt+4hi+{0..3}
      float4 b4 = *(const float4*)&bias[kt * 16 + 4 * hi];
      int2 tr2 = *(const int2*)&tree[kt * 8 + 2 * hi];
      float bb[4] = { b4.x, b4.y, b4.z, b4.w };
      int tt[2] = { tr2.x, tr2.y };
      ushort8 v;
#pragma unroll
      for (int p = 0; p < 2; ++p) {
        float l1 = lacc[2 * p + 1] + bb[2 * p + 1];
        float l0 = (tt[p] == -1) ? l1 : (lacc[2 * p] + bb[2 * p]);
        float e0 = __expf(-fabsf(l0)); float sp0 = __logf(1.f + e0);
        float ls0 = (l0 >= 0.f) ? -sp0 : l0 - sp0;
        float e1 = __expf(-fabsf(l1)); float sp1 = __logf(1.f + e1);
        float ls1 = (l1 >= 0.f) ? -sp1 : l1 - sp1;
        v[4 * p + 0] = f2bf(ls0);
        v[4 * p + 1] = f2bf(ls1);
        v[4 * p + 2] = f2bf(ls0 - l0);
        v[4 * p + 3] = f2bf(ls1 - l1);
      }
      *(ushort8*)&Bs[buf][w * 16 + fr][kq] = v;   // K-slots 8hi.. == global k0+8hi.. ✓
    }
    // --- A fragments straight from global (L2-resident, 64B-coalesced)
    bf16x8 a0 = *(const bf16x8*)(Ag + k0);
    bf16x8 a1 = *(const bf16x8*)(Ag + (size_t)16 * KDIM + k0);
    __syncthreads();          // dbuf + 1 barrier: write(buf) || read(buf) separated
    bf16x8 b[4];
#pragma unroll
    for (int n = 0; n < 4; ++n) b[n] = *(const bf16x8*)&Bs[buf][n * 16 + fr][kq];
#pragma unroll
    for (int n = 0; n < 4; ++n) {
      acc[0][n] = __builtin_amdgcn_mfma_f32_16x16x32_bf16(a0, b[n], acc[0][n], 0, 0, 0);
      acc[1][n] = __builtin_amdgcn_mfma_f32_16x16x32_bf16(a1, b[n], acc[1][n], 0, 0, 0);
    }
    buf ^= 1;
  }
  // C/D: col=lane&15 (n), row=(lane>>4)*4+reg (m). Coalesced 64B-per-fr stores.
  float* Pp = part + (size_t)s * (256 * 4096) + (size_t)(w * 32) * 4096 + n0;
  int rq = hi * 4;
#pragma unroll
  for (int m = 0; m < 2; ++m)
#pragma unroll
    for (int n = 0; n < 4; ++n)
#pragma unroll
      for (int r = 0; r < 4; ++r)
        Pp[(m * 16 + rq + r) * 4096 + n * 16 + fr] = acc[m][n][r];
}

// ---------------- Kernel 3: reduce 8 partials -> d_out ----------------
__global__ __launch_bounds__(256) void reduce8(const float* __restrict__ part,
                                               float* __restrict__ out) {
  int t = blockIdx.x * 256 + threadIdx.x;  // 262144 threads x float4
  f32x4 s = (f32x4){0.f, 0.f, 0.f, 0.f};
#pragma unroll
  for (int q = 0; q < 8; ++q)
    s += *(const f32x4*)&part[(size_t)q * (256 * 4096) + (size_t)t * 4];
  *(f32x4*)&out[(size_t)t * 4] = s;
}

extern "C" void kernel_launch(void* const* d_in, const int* in_sizes, int n_in,
                              void* d_out, int out_size, void* d_ws, size_t ws_size,
                              hipStream_t stream) {
  const float* x    = (const float*)d_in[0];
  const float* z    = (const float*)d_in[1];
  const float* W    = (const float*)d_in[2];
  const float* bias = (const float*)d_in[3];
  const int*   tree = (const int*)d_in[4];
  float* out = (float*)d_out;

  unsigned short* Amat = (unsigned short*)d_ws;                     // 1,605,632 B
  unsigned short* zb   = (unsigned short*)((char*)d_ws + 1605632);  //   524,288 B
  unsigned short* Wt   = (unsigned short*)((char*)d_ws + 2129920);  //   200,704 B
  float*          part = (float*)((char*)d_ws + 2330624);           // 33,554,432 B

  prep<<<dim3(1378), 256, 0, stream>>>(x, z, W, tree, Amat, zb, Wt);
  gemm_fused<<<dim3(512), 512, 0, stream>>>(Amat, zb, Wt, bias, tree, part);
  reduce8<<<dim3(1024), 256, 0, stream>>>(part, out);
}

// Round 8
// 42.892 us; speedup vs baseline: 1.1001x; 1.1001x over previous
//
#include <hip/hip_runtime.h>

#define NF   784
#define ZD   64
#define BXN  256
#define BZN  4096
#define KDIM 3136    // 4*NF
#define LCOL 1568    // 2*NF logit columns

typedef __attribute__((ext_vector_type(8))) short bf16x8;
typedef __attribute__((ext_vector_type(4))) float f32x4;
typedef __attribute__((ext_vector_type(8))) unsigned short ushort8;

__device__ __forceinline__ unsigned short f2bf(float f) {
  unsigned u = __float_as_uint(f);
  u += 0x7fff + ((u >> 16) & 1);   // round-to-nearest-even
  return (unsigned short)(u >> 16);
}

// ---------------- Kernel 1: prep (fused) ----------------
__global__ __launch_bounds__(256) void prep(const float* __restrict__ x,
                                            const float* __restrict__ z,
                                            const float* __restrict__ W,
                                            const int* __restrict__ tree,
                                            unsigned short* __restrict__ Amat,
                                            unsigned short* __restrict__ zb,
                                            unsigned short* __restrict__ Wt) {
  int bid = blockIdx.x, tid = threadIdx.x;
  if (bid < 1024) {                       // ---- build_a
    int b = bid >> 2;
    int j = (bid & 3) * 256 + tid;
    if (j >= NF) return;
    float xb = x[b * NF + j];
    int idx = tree[j];
    int gidx = idx < 0 ? idx + NF : idx;  // JAX negative-index wrap
    float xt = x[b * NF + gidx];
    ushort4 v;
    v.x = f2bf((1.f - xt) * xb);
    v.y = f2bf(xt * xb);
    v.z = f2bf((1.f - xt) * (1.f - xb));
    v.w = f2bf(xt * (1.f - xb));
    *(ushort4*)&Amat[(size_t)b * KDIM + 4 * j] = v;
  } else if (bid < 1280) {                // ---- z -> bf16
    int t = (bid - 1024) * 256 + tid;
    float4 v = *(const float4*)&z[t * 4];
    ushort4 o = { f2bf(v.x), f2bf(v.y), f2bf(v.z), f2bf(v.w) };
    *(ushort4*)&zb[t * 4] = o;
  } else {                                // ---- W -> Wt (transpose)
    int t = (bid - 1280) * 256 + tid;
    int c = t >> 4, k0 = (t & 15) * 4;
    ushort4 o;
    o.x = f2bf(W[(k0 + 0) * LCOL + c]);
    o.y = f2bf(W[(k0 + 1) * LCOL + c]);
    o.z = f2bf(W[(k0 + 2) * LCOL + c]);
    o.w = f2bf(W[(k0 + 3) * LCOL + c]);
    *(ushort4*)&Wt[c * 64 + k0] = o;
  }
}

// ---------------- Kernel 2: FUSED logits+logsigmoid+GEMM, pipelined ----------------
// R6 structure (best measured). NEW: part stores are NONTEMPORAL so the 33.5 MB
// stream does not evict Amat/Wt/zb from L2 (L2-thrash theory).
#define LP 40
__global__ __launch_bounds__(256) void gemm_fused(const unsigned short* __restrict__ Amat,
                                                  const unsigned short* __restrict__ zb,
                                                  const unsigned short* __restrict__ Wt,
                                                  const float* __restrict__ bias,
                                                  const int* __restrict__ tree,
                                                  float* __restrict__ part) {
  __shared__ unsigned short As[2][256][LP];  // 40960 B
  __shared__ unsigned short Bs[2][64][LP];   // 10240 B
  int bid = blockIdx.x;                      // 512 = 64 n-tiles x 8 k-splits
  int s = bid & 7, nt = bid >> 3;
  int n0 = nt * 64;
  int kt0 = s * 12 + (s < 2 ? s : 2);        // 98 = 13+13+12*6
  int nsteps = (s < 2) ? 13 : 12;
  int ktend = kt0 + nsteps;
  int tid = threadIdx.x;
  int w = tid >> 6, lane = tid & 63;
  int fr = lane & 15, hi = lane >> 4, kq = hi * 8;
  int srow = tid >> 2, scol = (tid & 3) * 8;
  const unsigned short* Ag = Amat + (size_t)srow * KDIM + scol;

  // z fragments: this wave's 16 z-rows, register-resident across all steps.
  const unsigned short* zp = zb + (size_t)(n0 + w * 16 + fr) * 64 + kq;
  bf16x8 zf0 = *(const bf16x8*)zp;
  bf16x8 zf1 = *(const bf16x8*)(zp + 32);

  f32x4 acc[4][4];
#pragma unroll
  for (int m = 0; m < 4; ++m)
#pragma unroll
    for (int n = 0; n < 4; ++n) acc[m][n] = (f32x4){0.f, 0.f, 0.f, 0.f};

  // ---- prologue: load step kt0's registers
  const unsigned short* wp = Wt + (size_t)(kt0 * 16 + fr) * 64 + kq;
  bf16x8 wf0 = *(const bf16x8*)wp;
  bf16x8 wf1 = *(const bf16x8*)(wp + 32);
  float4 b4  = *(const float4*)&bias[kt0 * 16 + 4 * hi];
  int2   tr2 = *(const int2*)&tree[kt0 * 8 + 2 * hi];
  int k0 = kt0 * 32;
  float4 ar0 = *(const float4*)(Ag + k0);
  float4 ar1 = *(const float4*)(Ag + (size_t)64 * KDIM + k0);
  float4 ar2 = *(const float4*)(Ag + (size_t)128 * KDIM + k0);
  float4 ar3 = *(const float4*)(Ag + (size_t)192 * KDIM + k0);

  int buf = 0;
  for (int i = 0; i < nsteps; ++i) {
    int kt = kt0 + i;
    // --- 1. logit MFMA for current step (operands already in regs)
    f32x4 lacc = (f32x4){0.f, 0.f, 0.f, 0.f};
    lacc = __builtin_amdgcn_mfma_f32_16x16x32_bf16(wf0, zf0, lacc, 0, 0, 0);
    lacc = __builtin_amdgcn_mfma_f32_16x16x32_bf16(wf1, zf1, lacc, 0, 0, 0);
    // --- 2. prefetch step kt+1 (clamped on last iter; values unused then)
    int ktn = (kt + 1 < ktend) ? kt + 1 : kt;
    const unsigned short* wpn = Wt + (size_t)(ktn * 16 + fr) * 64 + kq;
    bf16x8 wfn0 = *(const bf16x8*)wpn;
    bf16x8 wfn1 = *(const bf16x8*)(wpn + 32);
    float4 b4n  = *(const float4*)&bias[ktn * 16 + 4 * hi];
    int2   tr2n = *(const int2*)&tree[ktn * 8 + 2 * hi];
    int k0n = ktn * 32;
    float4 arn0 = *(const float4*)(Ag + k0n);
    float4 arn1 = *(const float4*)(Ag + (size_t)64 * KDIM + k0n);
    float4 arn2 = *(const float4*)(Ag + (size_t)128 * KDIM + k0n);
    float4 arn3 = *(const float4*)(Ag + (size_t)192 * KDIM + k0n);
    // --- 3. log-sigmoid epilogue (hides prefetch latency)
    float bb[4] = { b4.x, b4.y, b4.z, b4.w };
    int tt[2] = { tr2.x, tr2.y };
    ushort8 v;
#pragma unroll
    for (int p = 0; p < 2; ++p) {
      float l1 = lacc[2 * p + 1] + bb[2 * p + 1];
      float l0 = (tt[p] == -1) ? l1 : (lacc[2 * p] + bb[2 * p]);
      float e0 = __expf(-fabsf(l0)); float sp0 = __logf(1.f + e0);
      float ls0 = (l0 >= 0.f) ? -sp0 : l0 - sp0;
      float e1 = __expf(-fabsf(l1)); float sp1 = __logf(1.f + e1);
      float ls1 = (l1 >= 0.f) ? -sp1 : l1 - sp1;
      v[4 * p + 0] = f2bf(ls0);
      v[4 * p + 1] = f2bf(ls1);
      v[4 * p + 2] = f2bf(ls0 - l0);
      v[4 * p + 3] = f2bf(ls1 - l1);
    }
    // --- 4. stage current step to LDS[buf]
    *(float4*)&As[buf][srow      ][scol] = ar0;
    *(float4*)&As[buf][srow +  64][scol] = ar1;
    *(float4*)&As[buf][srow + 128][scol] = ar2;
    *(float4*)&As[buf][srow + 192][scol] = ar3;
    *(ushort8*)&Bs[buf][w * 16 + fr][kq] = v;
    __syncthreads();          // single barrier: dbuf makes write(k+1) race-free
    // --- 5. main MFMA
    bf16x8 a[4], b[4];
#pragma unroll
    for (int m = 0; m < 4; ++m) a[m] = *(const bf16x8*)&As[buf][w * 64 + m * 16 + fr][kq];
#pragma unroll
    for (int n = 0; n < 4; ++n) b[n] = *(const bf16x8*)&Bs[buf][n * 16 + fr][kq];
#pragma unroll
    for (int m = 0; m < 4; ++m)
#pragma unroll
      for (int n = 0; n < 4; ++n)
        acc[m][n] = __builtin_amdgcn_mfma_f32_16x16x32_bf16(a[m], b[n], acc[m][n], 0, 0, 0);
    // --- 6. rotate pipeline registers
    wf0 = wfn0; wf1 = wfn1; b4 = b4n; tr2 = tr2n;
    ar0 = arn0; ar1 = arn1; ar2 = arn2; ar3 = arn3;
    buf ^= 1;
  }
  // C/D: col = lane&15 (n), row = (lane>>4)*4 + reg (m).
  // NONTEMPORAL coalesced stores: bypass L2, keep Amat/Wt/zb resident.
  int col = lane & 15, rq = hi * 4;
  float* Pp = part + (size_t)s * (256 * 4096) + (size_t)(w * 64) * 4096 + n0;
#pragma unroll
  for (int m = 0; m < 4; ++m)
#pragma unroll
    for (int n = 0; n < 4; ++n)
#pragma unroll
      for (int r = 0; r < 4; ++r)
        __builtin_nontemporal_store(acc[m][n][r],
                                    &Pp[(m * 16 + rq + r) * 4096 + n * 16 + col]);
}

// ---------------- Kernel 3: reduce 8 partials -> d_out (nontemporal streaming) ----------------
__global__ __launch_bounds__(256) void reduce8(const float* __restrict__ part,
                                               float* __restrict__ out) {
  int t = blockIdx.x * 256 + threadIdx.x;  // 262144 threads x float4
  f32x4 s = (f32x4){0.f, 0.f, 0.f, 0.f};
#pragma unroll
  for (int q = 0; q < 8; ++q) {
    const f32x4* p = (const f32x4*)&part[(size_t)q * (256 * 4096) + (size_t)t * 4];
    s += __builtin_nontemporal_load(p);
  }
  f32x4* o = (f32x4*)&out[(size_t)t * 4];
  __builtin_nontemporal_store(s, o);
}

extern "C" void kernel_launch(void* const* d_in, const int* in_sizes, int n_in,
                              void* d_out, int out_size, void* d_ws, size_t ws_size,
                              hipStream_t stream) {
  const float* x    = (const float*)d_in[0];
  const float* z    = (const float*)d_in[1];
  const float* W    = (const float*)d_in[2];
  const float* bias = (const float*)d_in[3];
  const int*   tree = (const int*)d_in[4];
  float* out = (float*)d_out;

  unsigned short* Amat = (unsigned short*)d_ws;                     // 1,605,632 B
  unsigned short* zb   = (unsigned short*)((char*)d_ws + 1605632);  //   524,288 B
  unsigned short* Wt   = (unsigned short*)((char*)d_ws + 2129920);  //   200,704 B
  float*          part = (float*)((char*)d_ws + 2330624);           // 33,554,432 B

  prep<<<dim3(1378), 256, 0, stream>>>(x, z, W, tree, Amat, zb, Wt);
  gemm_fused<<<dim3(512), 256, 0, stream>>>(Amat, zb, Wt, bias, tree, part);
  reduce8<<<dim3(1024), 256, 0, stream>>>(part, out);
}